// Round 3
// baseline (590.101 us; speedup 1.0000x reference)
//
#include <hip/hip_runtime.h>

// Problem constants (fixed by reference setup_inputs)
#define B   64
#define C   256
#define H   64
#define W   64
#define HW  (H * W)
#define KPT 21

typedef float f32x4 __attribute__((ext_vector_type(4)));

// Kernel A: coverage-masked channel mean for both tensors. (R1 config: NSL=4
// slicing reverted — it was neutral-to-negative, A is fetch-bound not
// imbalance-bound.)
// grid = dim3(256, 2): x = b*4 + chunk (4 chunks of 1024 pixels), y = tensor.
// Each thread owns 4 consecutive pixels (one float4 in one image row).
// A pixel-group only feeds box_mean if some keypoint box touches it;
// ~48% of groups skip the whole 256-channel loop (exec-masked loads fetch
// ~40% fewer HBM lines). Skipped groups still write 0.0 so downstream reads
// never see poisoned workspace.
__global__ __launch_bounds__(256) void channel_mean_kernel(
    const float* __restrict__ f1, const float* __restrict__ f2,
    const int* __restrict__ pre1, const int* __restrict__ pre2,
    float* __restrict__ fm)
{
    const int t = blockIdx.y;
    const float* __restrict__ f  = t ? f2 : f1;
    const int* __restrict__ pre  = t ? pre2 : pre1;
    float* out = fm + (size_t)t * B * HW;

    const int b    = blockIdx.x >> 2;                              // batch
    const int pix0 = ((blockIdx.x & 3) * 256 + threadIdx.x) * 4;   // [0,4096)
    const int row  = pix0 >> 6;   // H index (bounds come from pre[...,0])
    const int col0 = pix0 & 63;   // W index (bounds come from pre[...,1])

    // Coverage test: does any keypoint box intersect [row] x [col0, col0+4)?
    // pre[...] indices are block-uniform -> scalar loads.
    bool needed = false;
    #pragma unroll
    for (int k = 0; k < KPT; ++k) {
        const int x = pre[(b * KPT + k) * 2 + 0];
        const int y = pre[(b * KPT + k) * 2 + 1];
        const int l = max(x - 6, 0);
        const int r = min(x + 6, 63);
        const int d = max(y - 6, 0);
        const int u = min(y + 6, 63);
        const bool hit = (row >= l) && (row < r) && (col0 < u) && (col0 + 4 > d);
        needed = needed || hit;
    }

    f32x4 acc = {0.f, 0.f, 0.f, 0.f};
    if (needed) {
        const float* base = f + (size_t)b * (C * HW) + pix0;
        #pragma unroll 16
        for (int c = 0; c < C; ++c) {
            const f32x4 v =
                __builtin_nontemporal_load((const f32x4*)(base + (size_t)c * HW));
            acc += v;
        }
    }
    acc *= (1.0f / (float)C);
    *(f32x4*)(out + (size_t)b * HW + pix0) = acc;
}

// Kernel BC: fused box means + batch mean + final MSE, single block.
// 768 threads = 12 waves. Pair p = t*21+k (42 pairs) handled as p = wave + 12*r,
// r = 0..3. Within a wave, lane = batch (B == 64 == wavefront). Each lane sums
// its whole clamped box: 12 rows x 4 aligned float4 column-groups = 48
// fully-unrolled independent L2-resident loads (latency-pipelined), masked by
// v_cndmask selects (never multiplies) so clamped/garbage addresses can't
// contribute. Wave-reduce over batches -> LDS feas[42] -> wave 0 does the MSE.
// Single dispatch replaces box_mean (42 blocks) + final_mse: one fewer launch
// gap, and all feas traffic stays in LDS.
__global__ __launch_bounds__(768) void box_mse_kernel(
    const float* __restrict__ fm,
    const int* __restrict__ pre1, const int* __restrict__ pre2,
    float* __restrict__ out)
{
    __shared__ float feas[2 * KPT];

    const int wave = threadIdx.x >> 6;
    const int lane = threadIdx.x & 63;
    const int b    = lane;

    #pragma unroll
    for (int rr = 0; rr < 4; ++rr) {
        const int p = wave + 12 * rr;
        if (p < 2 * KPT) {
            const int t = p / KPT;
            const int k = p - t * KPT;
            const int* __restrict__ pre = t ? pre2 : pre1;
            const float* base = fm + ((size_t)t * B + b) * HW;

            const int x = pre[(b * KPT + k) * 2 + 0];
            const int y = pre[(b * KPT + k) * 2 + 1];
            // torch slicing: rows from x bounds, cols from y bounds, excl upper.
            const int l = max(x - 6, 0);
            const int r = min(x + 6, 63);
            const int d = max(y - 6, 0);
            const int u = min(y + 6, 63);
            const int gbase = d >> 2;

            float s = 0.f;
            #pragma unroll
            for (int i = 0; i < 12; ++i) {
                const int rw  = l + i;
                const int rwc = rw < 63 ? rw : 63;   // address clamp (masked)
                const bool okr = rw < r;
                #pragma unroll
                for (int jj = 0; jj < 4; ++jj) {
                    const int g0  = gbase + jj;
                    const bool okg = g0 < 16;
                    const int g   = okg ? g0 : 15;    // address clamp (masked)
                    const f32x4 v = *(const f32x4*)(base + rwc * W + g * 4);
                    #pragma unroll
                    for (int cc = 0; cc < 4; ++cc) {
                        const int col = g0 * 4 + cc;
                        // select, NOT multiply: immune to garbage values
                        s += (okr && okg && (col >= d) && (col < u)) ? v[cc] : 0.f;
                    }
                }
            }
            float mean = s / (float)((r - l) * (u - d));

            // 64-lane reduction: sum of box means over batch
            #pragma unroll
            for (int off = 32; off > 0; off >>= 1)
                mean += __shfl_xor(mean, off, 64);

            if (lane == 0)
                feas[p] = mean * (1.0f / (float)B);
        }
    }

    __syncthreads();

    if (wave == 0) {
        float v = 0.f;
        if (lane < KPT) {
            const float diff = feas[lane] - 0.999f * feas[KPT + lane];
            v = diff * diff;
        }
        #pragma unroll
        for (int off = 32; off > 0; off >>= 1)
            v += __shfl_down(v, off, 64);
        if (lane == 0)
            out[0] = v * (1.0f / (float)KPT);
    }
}

extern "C" void kernel_launch(void* const* d_in, const int* in_sizes, int n_in,
                              void* d_out, int out_size, void* d_ws, size_t ws_size,
                              hipStream_t stream)
{
    const float* f1  = (const float*)d_in[0];
    const float* f2  = (const float*)d_in[1];
    const int*  pre1 = (const int*)d_in[2];
    const int*  pre2 = (const int*)d_in[3];

    float* fm = (float*)d_ws;              // 2 * 64 * 4096 floats = 2 MB

    channel_mean_kernel<<<dim3(B * 4, 2), 256, 0, stream>>>(f1, f2, pre1, pre2, fm);
    box_mse_kernel<<<1, 768, 0, stream>>>(fm, pre1, pre2, (float*)d_out);
}

// Round 4
// 475.608 us; speedup vs baseline: 1.2407x; 1.2407x over previous
//
#include <hip/hip_runtime.h>

// Problem constants (fixed by reference setup_inputs)
#define B   64
#define C   256
#define H   64
#define W   64
#define HW  (H * W)
#define KPT 21

typedef float f32x4 __attribute__((ext_vector_type(4)));

// Kernel A: coverage-masked channel mean for both tensors.
// grid = dim3(256, 2): x = b*4 + chunk (4 chunks of 1024 pixels), y = tensor select.
// Each thread owns 4 consecutive pixels (one float4 in one image row).
// A pixel-group only feeds box_mean if some keypoint box touches it; ~48% of
// lanes skip the whole 256-channel loop. Mandatory HBM fetch is the union of
// boxes at 64B-line granularity (~83% of 512 MB ~= 425 MB ~= 67 us), so this
// kernel is within ~5% of its data-dependent fetch floor (R2's 4x-occupancy
// experiment confirmed: more waves changed nothing).
// Skipped groups still write 0.0 so downstream reads never see poisoned ws.
__global__ __launch_bounds__(256) void channel_mean_kernel(
    const float* __restrict__ f1, const float* __restrict__ f2,
    const int* __restrict__ pre1, const int* __restrict__ pre2,
    float* __restrict__ fm)
{
    const int t = blockIdx.y;
    const float* __restrict__ f  = t ? f2 : f1;
    const int* __restrict__ pre  = t ? pre2 : pre1;
    float* out = fm + (size_t)t * B * HW;

    const int b    = blockIdx.x >> 2;                              // batch
    const int pix0 = ((blockIdx.x & 3) * 256 + threadIdx.x) * 4;   // [0,4096)
    const int row  = pix0 >> 6;   // H index (bounds come from pre[...,0])
    const int col0 = pix0 & 63;   // W index (bounds come from pre[...,1])

    // Coverage test: does any keypoint box intersect [row] x [col0, col0+4)?
    // pre[...] indices are block-uniform -> scalar loads.
    bool needed = false;
    #pragma unroll
    for (int k = 0; k < KPT; ++k) {
        const int x = pre[(b * KPT + k) * 2 + 0];
        const int y = pre[(b * KPT + k) * 2 + 1];
        const int l = max(x - 6, 0);
        const int r = min(x + 6, 63);
        const int d = max(y - 6, 0);
        const int u = min(y + 6, 63);
        const bool hit = (row >= l) && (row < r) && (col0 < u) && (col0 + 4 > d);
        needed = needed || hit;
    }

    f32x4 acc = {0.f, 0.f, 0.f, 0.f};
    if (needed) {
        const float* base = f + (size_t)b * (C * HW) + pix0;
        #pragma unroll 16
        for (int c = 0; c < C; ++c) {
            const f32x4 v =
                __builtin_nontemporal_load((const f32x4*)(base + (size_t)c * HW));
            acc += v;
        }
    }
    acc *= (1.0f / (float)C);
    *(f32x4*)(out + (size_t)b * HW + pix0) = acc;
}

// Kernel B: per-keypoint box means + batch mean.
// grid = dim3(21, 2): one block per (keypoint, tensor). 256 threads:
//   j = tid&3 -> one of 4 aligned float4 column-groups, b = tid>>2 -> batch.
// 42 blocks spread across the XCDs that wrote fm (single-block fusion in R3
// serialized the whole 2 MB read through one CU: +115 us — never again).
// Each lane: 12 fully-unrolled INDEPENDENT float4 loads (4 lanes = 64B line,
// coalesced, latency-pipelined). Out-of-range rows/cols are clamped to valid
// fm addresses (never poison) and masked out via v_cndmask selects.
__global__ __launch_bounds__(256) void box_mean_kernel(
    const float* __restrict__ fm,
    const int* __restrict__ pre1, const int* __restrict__ pre2,
    float* __restrict__ feas)   // feas[0..20] = fea_c1, feas[21..41] = fea_c2
{
    const int k = blockIdx.x;
    const int t = blockIdx.y;
    const int j = threadIdx.x & 3;
    const int b = threadIdx.x >> 2;

    const int* __restrict__ pre = t ? pre2 : pre1;
    const float* base = fm + ((size_t)t * B + b) * HW;

    const int x = pre[(b * KPT + k) * 2 + 0];
    const int y = pre[(b * KPT + k) * 2 + 1];
    // torch slicing: rows from x bounds, cols from y bounds, exclusive upper.
    const int l = max(x - 6, 0);
    const int r = min(x + 6, 63);
    const int d = max(y - 6, 0);
    const int u = min(y + 6, 63);

    // This lane's column-group. Needed cols are <= 62 -> group <= 15; clamp
    // duplicates (g0 >= 16) are masked to zero via okg.
    const int g0  = (d >> 2) + j;
    const bool okg = g0 < 16;
    const int g   = okg ? g0 : 15;
    const int c0  = g * 4;

    float s = 0.f;
    #pragma unroll
    for (int i = 0; i < 12; ++i) {
        const int rw  = l + i;
        const int rwc = rw < 63 ? rw : 63;      // address clamp (masked anyway)
        const f32x4 v = *(const f32x4*)(base + rwc * W + c0);
        const bool okr = okg && (rw < r);
        #pragma unroll
        for (int cc = 0; cc < 4; ++cc) {
            const int col = c0 + cc;
            // select (v_cndmask), NOT multiply: immune to garbage values
            s += (okr && (col >= d) && (col < u)) ? v[cc] : 0.f;
        }
    }

    // reduce over the 4 column-group lanes -> box sum (all 4 lanes hold it)
    s += __shfl_xor(s, 1, 64);
    s += __shfl_xor(s, 2, 64);
    const float mean = s / (float)((r - l) * (u - d));

    // reduce the 16 batches in this wave (offsets 4..32 preserve lane&3)
    float vsum = mean;
    #pragma unroll
    for (int off = 4; off < 64; off <<= 1)
        vsum += __shfl_xor(vsum, off, 64);

    __shared__ float part[4];
    const int wave = threadIdx.x >> 6;
    if ((threadIdx.x & 63) == 0) part[wave] = vsum;
    __syncthreads();
    if (threadIdx.x == 0)
        feas[t * KPT + k] = (part[0] + part[1] + part[2] + part[3]) * (1.0f / (float)B);
}

// Kernel C: final MSE over 21 keypoints with momentum on fea_c2.
__global__ __launch_bounds__(64) void final_mse_kernel(
    const float* __restrict__ feas, float* __restrict__ out)
{
    const int k = threadIdx.x;
    float v = 0.f;
    if (k < KPT) {
        const float diff = feas[k] - 0.999f * feas[KPT + k];
        v = diff * diff;
    }
    #pragma unroll
    for (int off = 32; off > 0; off >>= 1)
        v += __shfl_down(v, off, 64);
    if (threadIdx.x == 0)
        out[0] = v * (1.0f / (float)KPT);
}

extern "C" void kernel_launch(void* const* d_in, const int* in_sizes, int n_in,
                              void* d_out, int out_size, void* d_ws, size_t ws_size,
                              hipStream_t stream)
{
    const float* f1  = (const float*)d_in[0];
    const float* f2  = (const float*)d_in[1];
    const int*  pre1 = (const int*)d_in[2];
    const int*  pre2 = (const int*)d_in[3];

    float* fm   = (float*)d_ws;            // 2 * 64 * 4096 floats = 2 MB
    float* feas = fm + 2 * B * HW;         // 42 floats

    channel_mean_kernel<<<dim3(B * 4, 2), 256, 0, stream>>>(f1, f2, pre1, pre2, fm);
    box_mean_kernel<<<dim3(KPT, 2), 256, 0, stream>>>(fm, pre1, pre2, feas);
    final_mse_kernel<<<1, 64, 0, stream>>>(feas, (float*)d_out);
}